// Round 8
// baseline (131.519 us; speedup 1.0000x reference)
//
#include <hip/hip_runtime.h>

// P2G quadratic B-spline scatter, MI355X — v14 (resubmit; round-7 bench was
// an infra failure: "MI355X container failed twice", no measurement taken).
// K1 occupancy attack (PPB 2048->1024) + K2 prescaled fixed-point.
//
// Evidence ledger:
//  v7  (182, PASS): u64@2^42 LDS atomics accurate (0.0039); K1 scatter-wall.
//  v8/v9 (FAIL 0.4043 bit-identical): 2^22 truncation — integer fixed point
//      needs >=2^42; counting-sort K1 was always correct.
//  v10 (378, PASS): fp32 ds atomicAdd ~4x slower than u64 path.
//  v11 (122.4, PASS): counting-sort K1 + two-pass u64 K2 + K3. Harness ws
//      re-poison fill = 44 us fixed tax. Decomp: fill 44, K1 ~35, K2 ~25, K3 ~10.
//  v12 (128.0, REGRESS): 93KB-LDS single-pass K2 -> 1 WG/CU. Occupancy loss
//      > pass savings.
//  v13 (121.4, PASS): XCD-paired K2 passes + shuffle-scan K1: only -1 us.
//      Post-mortem: K1 issue-cost ~5x less than its 84K cyc/CU -> K1 is
//      LATENCY-bound (3 WG/CU, 1.9 blocks/CU grid, 4 barriers + ~700cy
//      reservation atomic, nothing co-resident to hide them).
// v14:
//  K1: PPB=1024 -> 977 blocks (~3.8/CU), LDS 24KB -> 4 WG/CU (thread-capped).
//      2x co-resident blocks, half-length phases.
//  K2: wz pre-scaled by FXS (3 muls) instead of x2^42 inside all 27 cvts.
// Fallback (ws too small or B too large): v1 interleaved global-atomic path.

namespace {

constexpr int   G         = 64;
constexpr int   G3        = G * G * G;            // 262144
constexpr int   BIN       = 16;                   // cells per bin per axis
constexpr int   NBX       = G / BIN;              // 4 bins per axis
constexpr int   BINS_PB   = NBX * NBX * NBX;      // 64 bins per batch
constexpr int   TILE      = BIN + 2;              // 18 (halo -1..16)
constexpr int   TILE3     = TILE * TILE * TILE;   // 5832
constexpr int   CAP       = 2560;                 // slots per bin (avg ~1953)
constexpr int   PPB       = 1024;                 // particles per K1 block
constexpr int   NBINS_MAX = 512;                  // hist size (B<=8)
constexpr float EPS_CLIP  = 1e-5f;
constexpr float EPS_DIV   = 1e-7f;
constexpr float INV_DX    = 64.0f;                // 1/DX (exact pow2)
constexpr float FXS       = 4398046511104.0f;     // 2^42 fixed-point scale
constexpr float INV_FXS   = 1.0f / FXS;

static_assert((size_t)TILE3 * 8 < 65536, "K2 LDS over 64KB");

__device__ __forceinline__ float clip01(float v) {
    return fminf(fmaxf(v, EPS_CLIP), 1.0f - EPS_CLIP);
}

__device__ __forceinline__ void bspline_w(float f, float* w) {
    w[0] = 0.5f * (1.0f - f) * (1.0f - f);
    w[1] = 0.75f - (f - 0.5f) * (f - 0.5f);
    w[2] = 0.5f * f * f;
}

// ---------------- K1: block counting sort + linear coalesced drain --------

__global__ void __launch_bounds__(512)
bin_sort_mat(const float* __restrict__ pos,
             const float* __restrict__ prob,
             const int*   __restrict__ bidx,
             int*         __restrict__ cnt,    // nbins (<= NBINS_MAX)
             float4*      __restrict__ slots,  // nbins*CAP
             int L) {
    __shared__ unsigned int   s_hist[NBINS_MAX];
    __shared__ unsigned int   s_incl[NBINS_MAX];   // inclusive scan of hist
    __shared__ unsigned int   s_gbase[NBINS_MAX];  // gbase - excl (pre-biased)
    __shared__ unsigned int   s_wtot[8];           // per-wave scan totals
    __shared__ float4         s_pay[PPB];          // 16 KB sorted payload
    __shared__ unsigned short s_bin[PPB];          // bin id per sorted slot

    const int t    = threadIdx.x;
    const int base = blockIdx.x * PPB;
    const int np   = min(PPB, L - base);

    s_hist[t] = 0u;
    __syncthreads();

    // load + clip + bin + LDS histogram (rank = order within (block,bin))
    float4   pay[PPB / 512];
    int      pbin[PPB / 512];
    unsigned rank[PPB / 512];
#pragma unroll
    for (int k = 0; k < PPB / 512; ++k) {
        int i = base + k * 512 + t;
        pbin[k] = -1;
        if (i < L) {
            float px = clip01(pos[3 * i + 0]);
            float py = clip01(pos[3 * i + 1]);
            float pz = clip01(pos[3 * i + 2]);
            int bx = (int)(px * INV_DX);
            int by = (int)(py * INV_DX);
            int bz = (int)(pz * INV_DX);
            int b  = ((bidx[i] * NBX + (bx >> 4)) * NBX + (by >> 4)) * NBX
                     + (bz >> 4);
            pay[k]  = make_float4(px, py, pz, prob[i]);
            pbin[k] = b;
            rank[k] = atomicAdd(&s_hist[b], 1u);
        }
    }
    __syncthreads();

    // one global reservation atomic per non-empty (block,bin); overlap with
    // the wave-level inclusive scan of the histogram (no barriers in-wave).
    const unsigned c  = s_hist[t];
    const unsigned gb = c ? (unsigned)atomicAdd(&cnt[t], (int)c) : 0u;

    unsigned v = c;
#pragma unroll
    for (int d = 1; d < 64; d <<= 1) {
        unsigned o = __shfl_up(v, d, 64);
        if ((t & 63) >= d) v += o;
    }
    if ((t & 63) == 63) s_wtot[t >> 6] = v;
    __syncthreads();
    unsigned off = 0;
#pragma unroll
    for (int w = 0; w < 8; ++w)
        if (w < (t >> 6)) off += s_wtot[w];
    const unsigned incl = v + off;
    s_incl[t]  = incl;
    s_gbase[t] = gb - (incl - c);    // pre-biased: drain g = s_gbase[b] + j
    __syncthreads();

    // physical reorder into LDS (sorted position = excl[bin] + rank)
#pragma unroll
    for (int k = 0; k < PPB / 512; ++k) {
        if (pbin[k] >= 0) {
            int b = pbin[k];
            unsigned sp = s_incl[b] - s_hist[b] + rank[k];
            s_pay[sp] = pay[k];
            s_bin[sp] = (unsigned short)b;
        }
    }
    __syncthreads();

    // linear drain: consecutive sorted particles -> consecutive slot addrs
    for (int j = t; j < np; j += 512) {
        int b = s_bin[j];
        unsigned g = s_gbase[b] + (unsigned)j;   // gbase + (j - excl), mod 2^32
        if (g < CAP) slots[(size_t)b * CAP + g] = s_pay[j];
    }
}

// ---------------- K2: per-bin u64 tile, two XCD-paired passes -------------

__global__ void __launch_bounds__(512)
accumulate_bins_pass(const float4* __restrict__ slots,
                     const int*    __restrict__ cnt,
                     float*        __restrict__ tiles_w,    // nbins*TILE3
                     float*        __restrict__ tiles_wp) { // nbins*TILE3
    __shared__ unsigned long long t_acc[TILE3];   // 46.7 KB
    // XCD-paired mapping: bin's two passes are 8 blocks apart -> same XCD
    // (round-robin dispatch) -> pass B's slot reads hit that XCD's L2.
    const int x     = blockIdx.x;
    const int which = (x >> 3) & 1;               // 0: w, 1: w*p
    const int bin   = ((x >> 4) << 3) | (x & 7);
    const int tid   = threadIdx.x;

    for (int j = tid; j < TILE3; j += 512) t_acc[j] = 0ull;
    __syncthreads();

    const int n = min(cnt[bin], CAP);
    // bin = ((batch*4 + bbx)*4 + bby)*4 + bbz
    const int bx0 = ((bin >> 4) & 3) * BIN;
    const int by0 = ((bin >> 2) & 3) * BIN;
    const int bz0 = (bin & 3) * BIN;
    const float4* sbase = slots + (size_t)bin * CAP;

    for (int s = tid; s < n; s += 512) {
        float4 r = sbase[s];                         // coalesced 16B load
        float xp = r.x * INV_DX;                     // pos pre-clipped in K1
        float yp = r.y * INV_DX;
        float zp = r.z * INV_DX;
        int bx = (int)xp, by = (int)yp, bz = (int)zp;
        // defensive: an anomalous slot must never index LDS out of bounds
        int l0x = bx - bx0, l0y = by - by0, l0z = bz - bz0;
        if (((l0x | l0y | l0z) & ~15) != 0) continue;
        float wx[3], wy[3], wz[3];
        bspline_w(xp - (float)bx, wx);
        bspline_w(yp - (float)by, wy);
        bspline_w(zp - (float)bz, wz);
        // pre-scale z weights by 2^42 so the tap product is already fixed
        // point (saves a mul per tap vs scaling inside the convert)
        wz[0] *= FXS; wz[1] *= FXS; wz[2] *= FXS;
        float p = which ? r.w : 1.0f;                // unify both passes
#pragma unroll
        for (int a = 0; a < 3; ++a) {
            int ix = (l0x + a) * TILE;
#pragma unroll
            for (int cc = 0; cc < 3; ++cc) {
                int ixy = (ix + l0y + cc) * TILE;
                float wxy = wx[a] * wy[cc] * p;
#pragma unroll
                for (int e = 0; e < 3; ++e) {
                    float v = wxy * wz[e];
                    atomicAdd(&t_acc[ixy + l0z + e],
                              (unsigned long long)v);
                }
            }
        }
    }
    __syncthreads();

    float* gt = (which ? tiles_wp : tiles_w) + (size_t)bin * TILE3;
    for (int j = tid; j < TILE3; j += 512) {
        gt[j] = (float)t_acc[j] * INV_FXS;
    }
}

// ---------------- K3: gather overlapping tiles + divide -------------------

__global__ void finalize_tiles(const float* __restrict__ tiles_w,
                               const float* __restrict__ tiles_wp,
                               float*       __restrict__ out,
                               int total) {
    int c = blockIdx.x * blockDim.x + threadIdx.x;
    if (c >= total) return;
    int cz = c & 63, cy = (c >> 6) & 63, cx = (c >> 12) & 63, b = c >> 18;
    int bx = cx >> 4, mx = cx & 15;
    int by = cy >> 4, my = cy & 15;
    int bz = cz >> 4, mz = cz & 15;

    // per-axis list of (bin coord, tile-local index) covering this cell
    int xb[2], xl[2], nx = 1; xb[0] = bx; xl[0] = mx + 1;
    if (mx == 0 && bx > 0)            { xb[1] = bx - 1; xl[1] = TILE - 1; nx = 2; }
    else if (mx == 15 && bx < NBX - 1){ xb[1] = bx + 1; xl[1] = 0;        nx = 2; }
    int yb[2], yl[2], ny = 1; yb[0] = by; yl[0] = my + 1;
    if (my == 0 && by > 0)            { yb[1] = by - 1; yl[1] = TILE - 1; ny = 2; }
    else if (my == 15 && by < NBX - 1){ yb[1] = by + 1; yl[1] = 0;        ny = 2; }
    int zb[2], zl[2], nz = 1; zb[0] = bz; zl[0] = mz + 1;
    if (mz == 0 && bz > 0)            { zb[1] = bz - 1; zl[1] = TILE - 1; nz = 2; }
    else if (mz == 15 && bz < NBX - 1){ zb[1] = bz + 1; zl[1] = 0;        nz = 2; }

    float w = 0.f, wp = 0.f;
    for (int i = 0; i < nx; ++i)
        for (int j = 0; j < ny; ++j)
            for (int k = 0; k < nz; ++k) {
                int bin = ((b * NBX + xb[i]) * NBX + yb[j]) * NBX + zb[k];
                size_t idx = (size_t)bin * TILE3
                             + (xl[i] * TILE + yl[j]) * TILE + zl[k];
                w  += tiles_w[idx];
                wp += tiles_wp[idx];
            }
    out[c] = wp / (w + EPS_DIV);
}

// ---------------- fallback kernels (v1) -----------------------------------

__global__ void scatter_interleaved(const float* __restrict__ pos,
                                    const float* __restrict__ prob,
                                    const int*   __restrict__ bidx,
                                    float2*      __restrict__ grid,
                                    int L) {
    int i = blockIdx.x * blockDim.x + threadIdx.x;
    if (i >= L) return;
    float xp = clip01(pos[3 * i + 0]) * INV_DX;
    float yp = clip01(pos[3 * i + 1]) * INV_DX;
    float zp = clip01(pos[3 * i + 2]) * INV_DX;
    int bx = (int)xp, by = (int)yp, bz = (int)zp;
    float wx[3], wy[3], wz[3];
    bspline_w(xp - (float)bx, wx);
    bspline_w(yp - (float)by, wy);
    bspline_w(zp - (float)bz, wz);
    float p = prob[i];
    float2* gbase = grid + (size_t)bidx[i] * G3;
#pragma unroll
    for (int a = 0; a < 3; ++a) {
        int tx = bx + a - 1;
        if (tx < 0 || tx >= G) continue;
#pragma unroll
        for (int c = 0; c < 3; ++c) {
            int ty = by + c - 1;
            if (ty < 0 || ty >= G) continue;
            float wxy = wx[a] * wy[c];
            int rowoff = (tx * G + ty) * G;
#pragma unroll
            for (int e = 0; e < 3; ++e) {
                int tz = bz + e - 1;
                if (tz < 0 || tz >= G) continue;
                float w = wxy * wz[e];
                float2* cell = gbase + rowoff + tz;
                atomicAdd(&cell->x, w);
                atomicAdd(&cell->y, w * p);
            }
        }
    }
}

__global__ void finalize_interleaved(const float2* __restrict__ grid,
                                     float* __restrict__ out, int n) {
    int i = blockIdx.x * blockDim.x + threadIdx.x;
    if (i >= n) return;
    float2 c = grid[i];
    out[i] = c.y / (c.x + EPS_DIV);
}

} // anonymous namespace

extern "C" void kernel_launch(void* const* d_in, const int* in_sizes, int n_in,
                              void* d_out, int out_size, void* d_ws, size_t ws_size,
                              hipStream_t stream) {
    const float* pos  = (const float*)d_in[0];
    const float* prob = (const float*)d_in[1];
    const int*   bidx = (const int*)d_in[2];
    float* out = (float*)d_out;

    const int L = in_sizes[1];            // prob has L elements
    const int B = out_size / G3;          // out_size == B * G3
    const int nbins = B * BINS_PB;

    const int threads = 256;
    const int k1blocks = (L + PPB - 1) / PPB;
    const int pblocks  = (L + threads - 1) / threads;
    const int fblocks  = (out_size + threads - 1) / threads;

    // ws: [tiles_w: nbins*TILE3*4B][tiles_wp: same][slots: nbins*CAP*16B][cnt]
    const size_t tilesw_bytes = (size_t)nbins * TILE3 * sizeof(float);
    const size_t slots_bytes  = (size_t)nbins * CAP * sizeof(float4);
    const size_t cnt_bytes    = (size_t)nbins * sizeof(int);
    const size_t need         = 2 * tilesw_bytes + slots_bytes + cnt_bytes;

    if (ws_size >= need && nbins <= NBINS_MAX && (nbins & 7) == 0) {
        float*  tiles_w  = (float*)d_ws;
        float*  tiles_wp = (float*)((char*)d_ws + tilesw_bytes);
        float4* slots    = (float4*)((char*)d_ws + 2 * tilesw_bytes);
        int*    cnt      = (int*)((char*)d_ws + 2 * tilesw_bytes + slots_bytes);

        hipMemsetAsync(cnt, 0, cnt_bytes, stream);
        bin_sort_mat<<<k1blocks, 512, 0, stream>>>(pos, prob, bidx,
                                                   cnt, slots, L);
        accumulate_bins_pass<<<nbins * 2, 512, 0, stream>>>(slots, cnt,
                                                            tiles_w, tiles_wp);
        finalize_tiles<<<fblocks, threads, 0, stream>>>(tiles_w, tiles_wp,
                                                        out, out_size);
    } else if (ws_size >= (size_t)out_size * 2 * sizeof(float)) {
        // v1 fallback: interleaved global-atomic scatter
        float2* grid = (float2*)d_ws;
        hipMemsetAsync(d_ws, 0, (size_t)out_size * 2 * sizeof(float), stream);
        scatter_interleaved<<<pblocks, threads, 0, stream>>>(pos, prob, bidx, grid, L);
        finalize_interleaved<<<fblocks, threads, 0, stream>>>(grid, out, out_size);
    }
}

// Round 9
// 130.392 us; speedup vs baseline: 1.0086x; 1.0086x over previous
//
#include <hip/hip_runtime.h>

// P2G quadratic B-spline scatter, MI355X — v15: v13 K1 + z-split single-pass
// K2 (both w & wp per block, half-tile each) + float2 K3.
//
// Evidence ledger:
//  v7  (182, PASS): u64@2^42 LDS atomics accurate; K1 global-scatter wall.
//  v8/v9 (FAIL 0.4043 bit-identical): low-scale fixed-point truncation is
//      uncorrelated between w and wp -> ratio blows up at tiny-w cells.
//      Scale must be >= 2^42. Counting-sort K1 was always correct.
//  v10 (378, PASS): fp32 ds atomicAdd ~4x slower than u64; reservation-only
//      K1 (4 WG/CU) ALSO ~35us -> K1 occupancy never the limit.
//  v11 (122.4, PASS): sort K1 + two-pass u64 K2 + float2 K3. fill=44us tax.
//  v12 (128.0, REGRESS): 93KB single-pass K2 -> 1 WG/CU. Reverted.
//  v13 (121.4, PASS): XCD-paired passes + shuffle scan. Best so far.
//  v14 (131.5, REGRESS): PPB 1024 halved sort-run length 4->2 slots ->
//      drain stores fragment to 32B partial lines + 1.7x reservation
//      atomics. K1 is TRANSACTION-bound; run length is protected. PPB=2048.
// v15:
//  K2: z-split single pass. Two blocks per bin own z-planes [0,8] / [9,17]
//      of the 18^3 tile (2 x 23.3KB u64 LDS = 46.6KB, 3 WG/CU). Each block
//      accumulates BOTH w and wp. Tap cells partition exactly (atomic count
//      unchanged); slot fetch + weight compute drop 2.0x -> 1.125x (only
//      l0z in {7,8} straddles). XCD pairing kept (halves 8 blocks apart).
//  K3: v11 float2 gather (half the load transactions of SoA).
// Fallback (ws too small or B too large): v1 interleaved global-atomic path.

namespace {

constexpr int   G         = 64;
constexpr int   G3        = G * G * G;            // 262144
constexpr int   BIN       = 16;                   // cells per bin per axis
constexpr int   NBX       = G / BIN;              // 4 bins per axis
constexpr int   BINS_PB   = NBX * NBX * NBX;      // 64 bins per batch
constexpr int   TILE      = BIN + 2;              // 18 (halo -1..16)
constexpr int   TILE3     = TILE * TILE * TILE;   // 5832
constexpr int   HZ        = 9;                    // z-planes per K2 half
constexpr int   HSIZE     = TILE * TILE * HZ;     // 2916 cells per half
constexpr int   CAP       = 2560;                 // slots per bin (avg ~1953)
constexpr int   PPB       = 2048;                 // particles per K1 block
constexpr int   NBINS_MAX = 512;                  // hist size (B<=8)
constexpr float EPS_CLIP  = 1e-5f;
constexpr float EPS_DIV   = 1e-7f;
constexpr float INV_DX    = 64.0f;                // 1/DX (exact pow2)
constexpr float FXS       = 4398046511104.0f;     // 2^42 fixed-point scale
constexpr float INV_FXS   = 1.0f / FXS;

static_assert((size_t)HSIZE * 16 < 65536, "K2 LDS over 64KB");

__device__ __forceinline__ float clip01(float v) {
    return fminf(fmaxf(v, EPS_CLIP), 1.0f - EPS_CLIP);
}

__device__ __forceinline__ void bspline_w(float f, float* w) {
    w[0] = 0.5f * (1.0f - f) * (1.0f - f);
    w[1] = 0.75f - (f - 0.5f) * (f - 0.5f);
    w[2] = 0.5f * f * f;
}

// ---------------- K1: block counting sort + linear coalesced drain --------

__global__ void __launch_bounds__(512)
bin_sort_mat(const float* __restrict__ pos,
             const float* __restrict__ prob,
             const int*   __restrict__ bidx,
             int*         __restrict__ cnt,    // nbins (<= NBINS_MAX)
             float4*      __restrict__ slots,  // nbins*CAP
             int L) {
    __shared__ unsigned int   s_hist[NBINS_MAX];
    __shared__ unsigned int   s_incl[NBINS_MAX];   // inclusive scan of hist
    __shared__ unsigned int   s_gbase[NBINS_MAX];  // gbase - excl (pre-biased)
    __shared__ unsigned int   s_wtot[8];           // per-wave scan totals
    __shared__ float4         s_pay[PPB];          // 32 KB sorted payload
    __shared__ unsigned short s_bin[PPB];          // bin id per sorted slot

    const int t    = threadIdx.x;
    const int base = blockIdx.x * PPB;
    const int np   = min(PPB, L - base);

    s_hist[t] = 0u;
    __syncthreads();

    // load + clip + bin + LDS histogram (rank = order within (block,bin))
    float4   pay[PPB / 512];
    int      pbin[PPB / 512];
    unsigned rank[PPB / 512];
#pragma unroll
    for (int k = 0; k < PPB / 512; ++k) {
        int i = base + k * 512 + t;
        pbin[k] = -1;
        if (i < L) {
            float px = clip01(pos[3 * i + 0]);
            float py = clip01(pos[3 * i + 1]);
            float pz = clip01(pos[3 * i + 2]);
            int bx = (int)(px * INV_DX);
            int by = (int)(py * INV_DX);
            int bz = (int)(pz * INV_DX);
            int b  = ((bidx[i] * NBX + (bx >> 4)) * NBX + (by >> 4)) * NBX
                     + (bz >> 4);
            pay[k]  = make_float4(px, py, pz, prob[i]);
            pbin[k] = b;
            rank[k] = atomicAdd(&s_hist[b], 1u);
        }
    }
    __syncthreads();

    // one global reservation atomic per non-empty (block,bin); overlap with
    // the wave-level inclusive scan of the histogram (no barriers in-wave).
    const unsigned c  = s_hist[t];
    const unsigned gb = c ? (unsigned)atomicAdd(&cnt[t], (int)c) : 0u;

    unsigned v = c;
#pragma unroll
    for (int d = 1; d < 64; d <<= 1) {
        unsigned o = __shfl_up(v, d, 64);
        if ((t & 63) >= d) v += o;
    }
    if ((t & 63) == 63) s_wtot[t >> 6] = v;
    __syncthreads();
    unsigned off = 0;
#pragma unroll
    for (int w = 0; w < 8; ++w)
        if (w < (t >> 6)) off += s_wtot[w];
    const unsigned incl = v + off;
    s_incl[t]  = incl;
    s_gbase[t] = gb - (incl - c);    // pre-biased: drain g = s_gbase[b] + j
    __syncthreads();

    // physical reorder into LDS (sorted position = excl[bin] + rank)
#pragma unroll
    for (int k = 0; k < PPB / 512; ++k) {
        if (pbin[k] >= 0) {
            int b = pbin[k];
            unsigned sp = s_incl[b] - s_hist[b] + rank[k];
            s_pay[sp] = pay[k];
            s_bin[sp] = (unsigned short)b;
        }
    }
    __syncthreads();

    // linear drain: consecutive sorted particles -> consecutive slot addrs
    for (int j = t; j < np; j += 512) {
        int b = s_bin[j];
        unsigned g = s_gbase[b] + (unsigned)j;   // gbase + (j - excl), mod 2^32
        if (g < CAP) slots[(size_t)b * CAP + g] = s_pay[j];
    }
}

// ------- K2: z-split single pass — each block: half tile, both w & wp -----

__global__ void __launch_bounds__(512)
accumulate_bins_zsplit(const float4* __restrict__ slots,
                       const int*    __restrict__ cnt,
                       float2*       __restrict__ tiles) {  // nbins*TILE3
    __shared__ unsigned long long t_w[HSIZE];    // 23.3 KB
    __shared__ unsigned long long t_wp[HSIZE];   // 23.3 KB
    // XCD-paired mapping: bin's two halves are 8 blocks apart -> same XCD
    // (round-robin dispatch) -> second half's slot reads hit that XCD's L2.
    const int x     = blockIdx.x;
    const int h     = (x >> 3) & 1;               // z-half: 0 -> [0,8], 1 -> [9,17]
    const int bin   = ((x >> 4) << 3) | (x & 7);
    const int tid   = threadIdx.x;
    const int zbase = HZ * h;

    for (int j = tid; j < HSIZE; j += 512) { t_w[j] = 0ull; t_wp[j] = 0ull; }
    __syncthreads();

    const int n = min(cnt[bin], CAP);
    // bin = ((batch*4 + bbx)*4 + bby)*4 + bbz
    const int bx0 = ((bin >> 4) & 3) * BIN;
    const int by0 = ((bin >> 2) & 3) * BIN;
    const int bz0 = (bin & 3) * BIN;
    const float4* sbase = slots + (size_t)bin * CAP;

    for (int s = tid; s < n; s += 512) {
        float4 r = sbase[s];                         // coalesced 16B load
        float xp = r.x * INV_DX;                     // pos pre-clipped in K1
        float yp = r.y * INV_DX;
        float zp = r.z * INV_DX;
        int bx = (int)xp, by = (int)yp, bz = (int)zp;
        // defensive: an anomalous slot must never index LDS out of bounds
        int l0x = bx - bx0, l0y = by - by0, l0z = bz - bz0;
        if (((l0x | l0y | l0z) & ~15) != 0) continue;
        // particle taps tile-z [l0z, l0z+2]; this half covers [zbase, zbase+8]
        int zr = l0z - zbase;                        // tap e lands iff 0<=zr+e<=8
        if (zr + 2 < 0 || zr > 8) continue;
        float wx[3], wy[3], wz[3];
        bspline_w(xp - (float)bx, wx);
        bspline_w(yp - (float)by, wy);
        bspline_w(zp - (float)bz, wz);
        wz[0] *= FXS; wz[1] *= FXS; wz[2] *= FXS;    // pre-scaled fixed point
        float p = r.w;
#pragma unroll
        for (int a = 0; a < 3; ++a) {
            int ix = (l0x + a) * TILE;
#pragma unroll
            for (int cc = 0; cc < 3; ++cc) {
                float wxy  = wx[a] * wy[cc];
                float wxyp = wxy * p;
                int row = (ix + l0y + cc) * HZ;
#pragma unroll
                for (int e = 0; e < 3; ++e) {
                    int tz = zr + e;
                    if ((unsigned)tz > 8u) continue;   // not in this half
                    int ci = row + tz;
                    atomicAdd(&t_w[ci],  (unsigned long long)(wxy  * wz[e]));
                    atomicAdd(&t_wp[ci], (unsigned long long)(wxyp * wz[e]));
                }
            }
        }
    }
    __syncthreads();

    // write this half's z-planes into the interleaved float2 tile
    float2* gt = tiles + (size_t)bin * TILE3;
    for (int j = tid; j < HSIZE; j += 512) {
        int tz = j % HZ;
        int tt = j / HZ;                              // tt = tx*TILE + ty
        gt[tt * TILE + zbase + tz] =
            make_float2((float)t_w[j]  * INV_FXS,
                        (float)t_wp[j] * INV_FXS);
    }
}

// ---------------- K3: gather overlapping tiles + divide -------------------

__global__ void finalize_tiles(const float2* __restrict__ tiles,
                               float*        __restrict__ out,
                               int total) {
    int c = blockIdx.x * blockDim.x + threadIdx.x;
    if (c >= total) return;
    int cz = c & 63, cy = (c >> 6) & 63, cx = (c >> 12) & 63, b = c >> 18;
    int bx = cx >> 4, mx = cx & 15;
    int by = cy >> 4, my = cy & 15;
    int bz = cz >> 4, mz = cz & 15;

    // per-axis list of (bin coord, tile-local index) covering this cell
    int xb[2], xl[2], nx = 1; xb[0] = bx; xl[0] = mx + 1;
    if (mx == 0 && bx > 0)            { xb[1] = bx - 1; xl[1] = TILE - 1; nx = 2; }
    else if (mx == 15 && bx < NBX - 1){ xb[1] = bx + 1; xl[1] = 0;        nx = 2; }
    int yb[2], yl[2], ny = 1; yb[0] = by; yl[0] = my + 1;
    if (my == 0 && by > 0)            { yb[1] = by - 1; yl[1] = TILE - 1; ny = 2; }
    else if (my == 15 && by < NBX - 1){ yb[1] = by + 1; yl[1] = 0;        ny = 2; }
    int zb[2], zl[2], nz = 1; zb[0] = bz; zl[0] = mz + 1;
    if (mz == 0 && bz > 0)            { zb[1] = bz - 1; zl[1] = TILE - 1; nz = 2; }
    else if (mz == 15 && bz < NBX - 1){ zb[1] = bz + 1; zl[1] = 0;        nz = 2; }

    float w = 0.f, wp = 0.f;
    for (int i = 0; i < nx; ++i)
        for (int j = 0; j < ny; ++j)
            for (int k = 0; k < nz; ++k) {
                int bin = ((b * NBX + xb[i]) * NBX + yb[j]) * NBX + zb[k];
                float2 v = tiles[(size_t)bin * TILE3
                                 + (xl[i] * TILE + yl[j]) * TILE + zl[k]];
                w += v.x; wp += v.y;
            }
    out[c] = wp / (w + EPS_DIV);
}

// ---------------- fallback kernels (v1) -----------------------------------

__global__ void scatter_interleaved(const float* __restrict__ pos,
                                    const float* __restrict__ prob,
                                    const int*   __restrict__ bidx,
                                    float2*      __restrict__ grid,
                                    int L) {
    int i = blockIdx.x * blockDim.x + threadIdx.x;
    if (i >= L) return;
    float xp = clip01(pos[3 * i + 0]) * INV_DX;
    float yp = clip01(pos[3 * i + 1]) * INV_DX;
    float zp = clip01(pos[3 * i + 2]) * INV_DX;
    int bx = (int)xp, by = (int)yp, bz = (int)zp;
    float wx[3], wy[3], wz[3];
    bspline_w(xp - (float)bx, wx);
    bspline_w(yp - (float)by, wy);
    bspline_w(zp - (float)bz, wz);
    float p = prob[i];
    float2* gbase = grid + (size_t)bidx[i] * G3;
#pragma unroll
    for (int a = 0; a < 3; ++a) {
        int tx = bx + a - 1;
        if (tx < 0 || tx >= G) continue;
#pragma unroll
        for (int c = 0; c < 3; ++c) {
            int ty = by + c - 1;
            if (ty < 0 || ty >= G) continue;
            float wxy = wx[a] * wy[c];
            int rowoff = (tx * G + ty) * G;
#pragma unroll
            for (int e = 0; e < 3; ++e) {
                int tz = bz + e - 1;
                if (tz < 0 || tz >= G) continue;
                float w = wxy * wz[e];
                float2* cell = gbase + rowoff + tz;
                atomicAdd(&cell->x, w);
                atomicAdd(&cell->y, w * p);
            }
        }
    }
}

__global__ void finalize_interleaved(const float2* __restrict__ grid,
                                     float* __restrict__ out, int n) {
    int i = blockIdx.x * blockDim.x + threadIdx.x;
    if (i >= n) return;
    float2 c = grid[i];
    out[i] = c.y / (c.x + EPS_DIV);
}

} // anonymous namespace

extern "C" void kernel_launch(void* const* d_in, const int* in_sizes, int n_in,
                              void* d_out, int out_size, void* d_ws, size_t ws_size,
                              hipStream_t stream) {
    const float* pos  = (const float*)d_in[0];
    const float* prob = (const float*)d_in[1];
    const int*   bidx = (const int*)d_in[2];
    float* out = (float*)d_out;

    const int L = in_sizes[1];            // prob has L elements
    const int B = out_size / G3;          // out_size == B * G3
    const int nbins = B * BINS_PB;

    const int threads = 256;
    const int k1blocks = (L + PPB - 1) / PPB;
    const int pblocks  = (L + threads - 1) / threads;
    const int fblocks  = (out_size + threads - 1) / threads;

    // ws layout: [tiles: nbins*TILE3*8B][slots: nbins*CAP*16B][cnt: nbins*4B]
    const size_t tiles_bytes = (size_t)nbins * TILE3 * sizeof(float2);
    const size_t slots_bytes = (size_t)nbins * CAP * sizeof(float4);
    const size_t cnt_bytes   = (size_t)nbins * sizeof(int);
    const size_t need        = tiles_bytes + slots_bytes + cnt_bytes;

    if (ws_size >= need && nbins <= NBINS_MAX && (nbins & 7) == 0) {
        float2* tiles = (float2*)d_ws;
        float4* slots = (float4*)((char*)d_ws + tiles_bytes);
        int*    cnt   = (int*)((char*)d_ws + tiles_bytes + slots_bytes);

        hipMemsetAsync(cnt, 0, cnt_bytes, stream);
        bin_sort_mat<<<k1blocks, 512, 0, stream>>>(pos, prob, bidx,
                                                   cnt, slots, L);
        accumulate_bins_zsplit<<<nbins * 2, 512, 0, stream>>>(slots, cnt,
                                                              tiles);
        finalize_tiles<<<fblocks, threads, 0, stream>>>(tiles, out, out_size);
    } else if (ws_size >= (size_t)out_size * 2 * sizeof(float)) {
        // v1 fallback: interleaved global-atomic scatter
        float2* grid = (float2*)d_ws;
        hipMemsetAsync(d_ws, 0, (size_t)out_size * 2 * sizeof(float), stream);
        scatter_interleaved<<<pblocks, threads, 0, stream>>>(pos, prob, bidx, grid, L);
        finalize_interleaved<<<fblocks, threads, 0, stream>>>(grid, out, out_size);
    }
}

// Round 10
// 118.499 us; speedup vs baseline: 1.1099x; 1.1004x over previous
//
#include <hip/hip_runtime.h>

// P2G quadratic B-spline scatter, MI355X — v16: v13 base, PPB 2048->4096
// (K1 run-length doubling; single-variable experiment).
//
// Evidence ledger:
//  v7  (182, PASS): u64@2^42 LDS atomics accurate; K1 global-scatter wall.
//  v8/v9 (FAIL 0.4043 bit-identical): fixed-point scale must be >=2^42
//      (uncorrelated w/wp truncation blows up tiny-w cells' ratio).
//  v10 (378, PASS): fp32 ds atomicAdd ~4x slower than u64; reservation-only
//      K1 (4 WG/CU) ALSO ~35us -> K1 occupancy never the limit.
//  v11 (122.4, PASS): sort K1 + two-pass u64 K2 + float2 K3. fill=44us tax.
//  v12 (128.0, REGRESS): 93KB single-pass K2 -> 1 WG/CU (but PROVED >64KB
//      static LDS works on gfx950).
//  v13 (121.4, PASS; BEST): XCD-paired K2 passes + shuffle scan.
//  v14 (131.5, REGRESS): PPB 1024 fragmented sort runs 4->2 slots (32B
//      partial lines) + 1.7x reservation atomics. Run length is protected.
//  v15 (130.4, REGRESS): z-split K2 — per-tap branch + 44% lane idling +
//      2x atomic issue density beat the 1.8x compute saving.
// v16: PPB=4096. Runs avg 8 slots = 128B = 2 full lines; reservation
//      atomics 0.25M->0.125M; store line-touches ~500K->~375K. LDS 78KB
//      (2 WG/CU, v12 precedent), 245 blocks ~1/CU all-concurrent.
//      K2/K3 bitwise-identical to v13 (+neutral wz prescale from v14).
// Fallback (ws too small or B too large): v1 interleaved global-atomic path.

namespace {

constexpr int   G         = 64;
constexpr int   G3        = G * G * G;            // 262144
constexpr int   BIN       = 16;                   // cells per bin per axis
constexpr int   NBX       = G / BIN;              // 4 bins per axis
constexpr int   BINS_PB   = NBX * NBX * NBX;      // 64 bins per batch
constexpr int   TILE      = BIN + 2;              // 18 (halo -1..16)
constexpr int   TILE3     = TILE * TILE * TILE;   // 5832
constexpr int   CAP       = 2560;                 // slots per bin (avg ~1953)
constexpr int   PPB       = 4096;                 // particles per K1 block
constexpr int   NBINS_MAX = 512;                  // hist size (B<=8)
constexpr float EPS_CLIP  = 1e-5f;
constexpr float EPS_DIV   = 1e-7f;
constexpr float INV_DX    = 64.0f;                // 1/DX (exact pow2)
constexpr float FXS       = 4398046511104.0f;     // 2^42 fixed-point scale
constexpr float INV_FXS   = 1.0f / FXS;

static_assert((size_t)TILE3 * 8 < 65536, "K2 LDS over 64KB");
static_assert((size_t)PPB * 18 + NBINS_MAX * 12 + 32 < 160 * 1024,
              "K1 LDS over 160KB");

__device__ __forceinline__ float clip01(float v) {
    return fminf(fmaxf(v, EPS_CLIP), 1.0f - EPS_CLIP);
}

__device__ __forceinline__ void bspline_w(float f, float* w) {
    w[0] = 0.5f * (1.0f - f) * (1.0f - f);
    w[1] = 0.75f - (f - 0.5f) * (f - 0.5f);
    w[2] = 0.5f * f * f;
}

// ---------------- K1: block counting sort + linear coalesced drain --------

__global__ void __launch_bounds__(512)
bin_sort_mat(const float* __restrict__ pos,
             const float* __restrict__ prob,
             const int*   __restrict__ bidx,
             int*         __restrict__ cnt,    // nbins (<= NBINS_MAX)
             float4*      __restrict__ slots,  // nbins*CAP
             int L) {
    __shared__ unsigned int   s_hist[NBINS_MAX];
    __shared__ unsigned int   s_incl[NBINS_MAX];   // inclusive scan of hist
    __shared__ unsigned int   s_gbase[NBINS_MAX];  // gbase - excl (pre-biased)
    __shared__ unsigned int   s_wtot[8];           // per-wave scan totals
    __shared__ float4         s_pay[PPB];          // 64 KB sorted payload
    __shared__ unsigned short s_bin[PPB];          // bin id per sorted slot

    const int t    = threadIdx.x;
    const int base = blockIdx.x * PPB;
    const int np   = min(PPB, L - base);

    s_hist[t] = 0u;
    __syncthreads();

    // load + clip + bin + LDS histogram (rank = order within (block,bin))
    float4   pay[PPB / 512];
    int      pbin[PPB / 512];
    unsigned rank[PPB / 512];
#pragma unroll
    for (int k = 0; k < PPB / 512; ++k) {
        int i = base + k * 512 + t;
        pbin[k] = -1;
        if (i < L) {
            float px = clip01(pos[3 * i + 0]);
            float py = clip01(pos[3 * i + 1]);
            float pz = clip01(pos[3 * i + 2]);
            int bx = (int)(px * INV_DX);
            int by = (int)(py * INV_DX);
            int bz = (int)(pz * INV_DX);
            int b  = ((bidx[i] * NBX + (bx >> 4)) * NBX + (by >> 4)) * NBX
                     + (bz >> 4);
            pay[k]  = make_float4(px, py, pz, prob[i]);
            pbin[k] = b;
            rank[k] = atomicAdd(&s_hist[b], 1u);
        }
    }
    __syncthreads();

    // one global reservation atomic per non-empty (block,bin); overlap with
    // the wave-level inclusive scan of the histogram (no barriers in-wave).
    const unsigned c  = s_hist[t];
    const unsigned gb = c ? (unsigned)atomicAdd(&cnt[t], (int)c) : 0u;

    unsigned v = c;
#pragma unroll
    for (int d = 1; d < 64; d <<= 1) {
        unsigned o = __shfl_up(v, d, 64);
        if ((t & 63) >= d) v += o;
    }
    if ((t & 63) == 63) s_wtot[t >> 6] = v;
    __syncthreads();
    unsigned off = 0;
#pragma unroll
    for (int w = 0; w < 8; ++w)
        if (w < (t >> 6)) off += s_wtot[w];
    const unsigned incl = v + off;
    s_incl[t]  = incl;
    s_gbase[t] = gb - (incl - c);    // pre-biased: drain g = s_gbase[b] + j
    __syncthreads();

    // physical reorder into LDS (sorted position = excl[bin] + rank)
#pragma unroll
    for (int k = 0; k < PPB / 512; ++k) {
        if (pbin[k] >= 0) {
            int b = pbin[k];
            unsigned sp = s_incl[b] - s_hist[b] + rank[k];
            s_pay[sp] = pay[k];
            s_bin[sp] = (unsigned short)b;
        }
    }
    __syncthreads();

    // linear drain: consecutive sorted particles -> consecutive slot addrs
    for (int j = t; j < np; j += 512) {
        int b = s_bin[j];
        unsigned g = s_gbase[b] + (unsigned)j;   // gbase + (j - excl), mod 2^32
        if (g < CAP) slots[(size_t)b * CAP + g] = s_pay[j];
    }
}

// ---------------- K2: per-bin u64 tile, two XCD-paired passes -------------

__global__ void __launch_bounds__(512)
accumulate_bins_pass(const float4* __restrict__ slots,
                     const int*    __restrict__ cnt,
                     float*        __restrict__ tiles_w,    // nbins*TILE3
                     float*        __restrict__ tiles_wp) { // nbins*TILE3
    __shared__ unsigned long long t_acc[TILE3];   // 46.7 KB
    // XCD-paired mapping: bin's two passes are 8 blocks apart -> same XCD
    // (round-robin dispatch) -> pass B's slot reads hit that XCD's L2.
    const int x     = blockIdx.x;
    const int which = (x >> 3) & 1;               // 0: w, 1: w*p
    const int bin   = ((x >> 4) << 3) | (x & 7);
    const int tid   = threadIdx.x;

    for (int j = tid; j < TILE3; j += 512) t_acc[j] = 0ull;
    __syncthreads();

    const int n = min(cnt[bin], CAP);
    // bin = ((batch*4 + bbx)*4 + bby)*4 + bbz
    const int bx0 = ((bin >> 4) & 3) * BIN;
    const int by0 = ((bin >> 2) & 3) * BIN;
    const int bz0 = (bin & 3) * BIN;
    const float4* sbase = slots + (size_t)bin * CAP;

    for (int s = tid; s < n; s += 512) {
        float4 r = sbase[s];                         // coalesced 16B load
        float xp = r.x * INV_DX;                     // pos pre-clipped in K1
        float yp = r.y * INV_DX;
        float zp = r.z * INV_DX;
        int bx = (int)xp, by = (int)yp, bz = (int)zp;
        // defensive: an anomalous slot must never index LDS out of bounds
        int l0x = bx - bx0, l0y = by - by0, l0z = bz - bz0;
        if (((l0x | l0y | l0z) & ~15) != 0) continue;
        float wx[3], wy[3], wz[3];
        bspline_w(xp - (float)bx, wx);
        bspline_w(yp - (float)by, wy);
        bspline_w(zp - (float)bz, wz);
        // pre-scale z weights by 2^42 so the tap product is already fixed
        // point (saves a mul per tap vs scaling inside the convert)
        wz[0] *= FXS; wz[1] *= FXS; wz[2] *= FXS;
        float p = which ? r.w : 1.0f;                // unify both passes
#pragma unroll
        for (int a = 0; a < 3; ++a) {
            int ix = (l0x + a) * TILE;
#pragma unroll
            for (int cc = 0; cc < 3; ++cc) {
                int ixy = (ix + l0y + cc) * TILE;
                float wxy = wx[a] * wy[cc] * p;
#pragma unroll
                for (int e = 0; e < 3; ++e) {
                    float v = wxy * wz[e];
                    atomicAdd(&t_acc[ixy + l0z + e],
                              (unsigned long long)v);
                }
            }
        }
    }
    __syncthreads();

    float* gt = (which ? tiles_wp : tiles_w) + (size_t)bin * TILE3;
    for (int j = tid; j < TILE3; j += 512) {
        gt[j] = (float)t_acc[j] * INV_FXS;
    }
}

// ---------------- K3: gather overlapping tiles + divide -------------------

__global__ void finalize_tiles(const float* __restrict__ tiles_w,
                               const float* __restrict__ tiles_wp,
                               float*       __restrict__ out,
                               int total) {
    int c = blockIdx.x * blockDim.x + threadIdx.x;
    if (c >= total) return;
    int cz = c & 63, cy = (c >> 6) & 63, cx = (c >> 12) & 63, b = c >> 18;
    int bx = cx >> 4, mx = cx & 15;
    int by = cy >> 4, my = cy & 15;
    int bz = cz >> 4, mz = cz & 15;

    // per-axis list of (bin coord, tile-local index) covering this cell
    int xb[2], xl[2], nx = 1; xb[0] = bx; xl[0] = mx + 1;
    if (mx == 0 && bx > 0)            { xb[1] = bx - 1; xl[1] = TILE - 1; nx = 2; }
    else if (mx == 15 && bx < NBX - 1){ xb[1] = bx + 1; xl[1] = 0;        nx = 2; }
    int yb[2], yl[2], ny = 1; yb[0] = by; yl[0] = my + 1;
    if (my == 0 && by > 0)            { yb[1] = by - 1; yl[1] = TILE - 1; ny = 2; }
    else if (my == 15 && by < NBX - 1){ yb[1] = by + 1; yl[1] = 0;        ny = 2; }
    int zb[2], zl[2], nz = 1; zb[0] = bz; zl[0] = mz + 1;
    if (mz == 0 && bz > 0)            { zb[1] = bz - 1; zl[1] = TILE - 1; nz = 2; }
    else if (mz == 15 && bz < NBX - 1){ zb[1] = bz + 1; zl[1] = 0;        nz = 2; }

    float w = 0.f, wp = 0.f;
    for (int i = 0; i < nx; ++i)
        for (int j = 0; j < ny; ++j)
            for (int k = 0; k < nz; ++k) {
                int bin = ((b * NBX + xb[i]) * NBX + yb[j]) * NBX + zb[k];
                size_t idx = (size_t)bin * TILE3
                             + (xl[i] * TILE + yl[j]) * TILE + zl[k];
                w  += tiles_w[idx];
                wp += tiles_wp[idx];
            }
    out[c] = wp / (w + EPS_DIV);
}

// ---------------- fallback kernels (v1) -----------------------------------

__global__ void scatter_interleaved(const float* __restrict__ pos,
                                    const float* __restrict__ prob,
                                    const int*   __restrict__ bidx,
                                    float2*      __restrict__ grid,
                                    int L) {
    int i = blockIdx.x * blockDim.x + threadIdx.x;
    if (i >= L) return;
    float xp = clip01(pos[3 * i + 0]) * INV_DX;
    float yp = clip01(pos[3 * i + 1]) * INV_DX;
    float zp = clip01(pos[3 * i + 2]) * INV_DX;
    int bx = (int)xp, by = (int)yp, bz = (int)zp;
    float wx[3], wy[3], wz[3];
    bspline_w(xp - (float)bx, wx);
    bspline_w(yp - (float)by, wy);
    bspline_w(zp - (float)bz, wz);
    float p = prob[i];
    float2* gbase = grid + (size_t)bidx[i] * G3;
#pragma unroll
    for (int a = 0; a < 3; ++a) {
        int tx = bx + a - 1;
        if (tx < 0 || tx >= G) continue;
#pragma unroll
        for (int c = 0; c < 3; ++c) {
            int ty = by + c - 1;
            if (ty < 0 || ty >= G) continue;
            float wxy = wx[a] * wy[c];
            int rowoff = (tx * G + ty) * G;
#pragma unroll
            for (int e = 0; e < 3; ++e) {
                int tz = bz + e - 1;
                if (tz < 0 || tz >= G) continue;
                float w = wxy * wz[e];
                float2* cell = gbase + rowoff + tz;
                atomicAdd(&cell->x, w);
                atomicAdd(&cell->y, w * p);
            }
        }
    }
}

__global__ void finalize_interleaved(const float2* __restrict__ grid,
                                     float* __restrict__ out, int n) {
    int i = blockIdx.x * blockDim.x + threadIdx.x;
    if (i >= n) return;
    float2 c = grid[i];
    out[i] = c.y / (c.x + EPS_DIV);
}

} // anonymous namespace

extern "C" void kernel_launch(void* const* d_in, const int* in_sizes, int n_in,
                              void* d_out, int out_size, void* d_ws, size_t ws_size,
                              hipStream_t stream) {
    const float* pos  = (const float*)d_in[0];
    const float* prob = (const float*)d_in[1];
    const int*   bidx = (const int*)d_in[2];
    float* out = (float*)d_out;

    const int L = in_sizes[1];            // prob has L elements
    const int B = out_size / G3;          // out_size == B * G3
    const int nbins = B * BINS_PB;

    const int threads = 256;
    const int k1blocks = (L + PPB - 1) / PPB;
    const int pblocks  = (L + threads - 1) / threads;
    const int fblocks  = (out_size + threads - 1) / threads;

    // ws: [tiles_w: nbins*TILE3*4B][tiles_wp: same][slots: nbins*CAP*16B][cnt]
    const size_t tilesw_bytes = (size_t)nbins * TILE3 * sizeof(float);
    const size_t slots_bytes  = (size_t)nbins * CAP * sizeof(float4);
    const size_t cnt_bytes    = (size_t)nbins * sizeof(int);
    const size_t need         = 2 * tilesw_bytes + slots_bytes + cnt_bytes;

    if (ws_size >= need && nbins <= NBINS_MAX && (nbins & 7) == 0) {
        float*  tiles_w  = (float*)d_ws;
        float*  tiles_wp = (float*)((char*)d_ws + tilesw_bytes);
        float4* slots    = (float4*)((char*)d_ws + 2 * tilesw_bytes);
        int*    cnt      = (int*)((char*)d_ws + 2 * tilesw_bytes + slots_bytes);

        hipMemsetAsync(cnt, 0, cnt_bytes, stream);
        bin_sort_mat<<<k1blocks, 512, 0, stream>>>(pos, prob, bidx,
                                                   cnt, slots, L);
        accumulate_bins_pass<<<nbins * 2, 512, 0, stream>>>(slots, cnt,
                                                            tiles_w, tiles_wp);
        finalize_tiles<<<fblocks, threads, 0, stream>>>(tiles_w, tiles_wp,
                                                        out, out_size);
    } else if (ws_size >= (size_t)out_size * 2 * sizeof(float)) {
        // v1 fallback: interleaved global-atomic scatter
        float2* grid = (float2*)d_ws;
        hipMemsetAsync(d_ws, 0, (size_t)out_size * 2 * sizeof(float), stream);
        scatter_interleaved<<<pblocks, threads, 0, stream>>>(pos, prob, bidx, grid, L);
        finalize_interleaved<<<fblocks, threads, 0, stream>>>(grid, out, out_size);
    }
}

// Round 11
// 117.974 us; speedup vs baseline: 1.1148x; 1.0045x over previous
//
#include <hip/hip_runtime.h>

// P2G quadratic B-spline scatter, MI355X — v17: v16 + K1 at 1024 threads
// (2x waves -> 2x memory-level parallelism; run structure untouched).
//
// Evidence ledger:
//  v7  (182, PASS): u64@2^42 LDS atomics accurate; K1 global-scatter wall.
//  v8/v9 (FAIL 0.4043 bit-identical): fixed-point scale must be >=2^42.
//  v10 (378, PASS): fp32 ds atomicAdd ~4x slower than u64.
//  v11 (122.4), v12 (128.0 REGRESS: 93KB K2 -> 1WG/CU),
//  v13 (121.4): XCD-paired K2 passes + shuffle scan.
//  v14 (131.5, REGRESS): PPB 1024 fragmented runs. Run length protected.
//  v15 (130.4, REGRESS): z-split K2 branch overhead.
//  v16 (118.5, BEST): PPB=4096 — runs avg 8 slots (2 full lines),
//      reservation atomics 0.25M->0.125M. Run-length theory CONFIRMED.
//      K1 now ~32us at 1 WG/CU x 8 waves -> latency exposure remains
//      (v13 post-mortem: measured ~5x issue cost).
// v17: K1 block = 1024 threads (16 waves). Same PPB=4096, same sort
//      structure, same LDS (78KB); per-thread arrays 8->4; scan uses
//      first 512 lanes. 2x outstanding scattered stores + reservation
//      atomics per CU, half-length phases. K2/K3 identical to v16.
// Fallback (ws too small or B too large): v1 interleaved global-atomic path.

namespace {

constexpr int   G         = 64;
constexpr int   G3        = G * G * G;            // 262144
constexpr int   BIN       = 16;                   // cells per bin per axis
constexpr int   NBX       = G / BIN;              // 4 bins per axis
constexpr int   BINS_PB   = NBX * NBX * NBX;      // 64 bins per batch
constexpr int   TILE      = BIN + 2;              // 18 (halo -1..16)
constexpr int   TILE3     = TILE * TILE * TILE;   // 5832
constexpr int   CAP       = 2560;                 // slots per bin (avg ~1953)
constexpr int   PPB       = 4096;                 // particles per K1 block
constexpr int   K1T       = 1024;                 // K1 threads per block
constexpr int   NBINS_MAX = 512;                  // hist size (B<=8)
constexpr float EPS_CLIP  = 1e-5f;
constexpr float EPS_DIV   = 1e-7f;
constexpr float INV_DX    = 64.0f;                // 1/DX (exact pow2)
constexpr float FXS       = 4398046511104.0f;     // 2^42 fixed-point scale
constexpr float INV_FXS   = 1.0f / FXS;

static_assert((size_t)TILE3 * 8 < 65536, "K2 LDS over 64KB");
static_assert((size_t)PPB * 18 + NBINS_MAX * 12 + 32 < 160 * 1024,
              "K1 LDS over 160KB");

__device__ __forceinline__ float clip01(float v) {
    return fminf(fmaxf(v, EPS_CLIP), 1.0f - EPS_CLIP);
}

__device__ __forceinline__ void bspline_w(float f, float* w) {
    w[0] = 0.5f * (1.0f - f) * (1.0f - f);
    w[1] = 0.75f - (f - 0.5f) * (f - 0.5f);
    w[2] = 0.5f * f * f;
}

// ---------------- K1: block counting sort + linear coalesced drain --------

__global__ void __launch_bounds__(K1T)
bin_sort_mat(const float* __restrict__ pos,
             const float* __restrict__ prob,
             const int*   __restrict__ bidx,
             int*         __restrict__ cnt,    // nbins (<= NBINS_MAX)
             float4*      __restrict__ slots,  // nbins*CAP
             int L) {
    __shared__ unsigned int   s_hist[NBINS_MAX];
    __shared__ unsigned int   s_incl[NBINS_MAX];   // inclusive scan of hist
    __shared__ unsigned int   s_gbase[NBINS_MAX];  // gbase - excl (pre-biased)
    __shared__ unsigned int   s_wtot[8];           // per-wave scan totals
    __shared__ float4         s_pay[PPB];          // 64 KB sorted payload
    __shared__ unsigned short s_bin[PPB];          // bin id per sorted slot

    const int t    = threadIdx.x;                  // 0..1023
    const int base = blockIdx.x * PPB;
    const int np   = min(PPB, L - base);

    if (t < NBINS_MAX) s_hist[t] = 0u;
    __syncthreads();

    // load + clip + bin + LDS histogram (rank = order within (block,bin))
    float4   pay[PPB / K1T];
    int      pbin[PPB / K1T];
    unsigned rank[PPB / K1T];
#pragma unroll
    for (int k = 0; k < PPB / K1T; ++k) {
        int i = base + k * K1T + t;
        pbin[k] = -1;
        if (i < L) {
            float px = clip01(pos[3 * i + 0]);
            float py = clip01(pos[3 * i + 1]);
            float pz = clip01(pos[3 * i + 2]);
            int bx = (int)(px * INV_DX);
            int by = (int)(py * INV_DX);
            int bz = (int)(pz * INV_DX);
            int b  = ((bidx[i] * NBX + (bx >> 4)) * NBX + (by >> 4)) * NBX
                     + (bz >> 4);
            pay[k]  = make_float4(px, py, pz, prob[i]);
            pbin[k] = b;
            rank[k] = atomicAdd(&s_hist[b], 1u);
        }
    }
    __syncthreads();

    // one global reservation atomic per non-empty (block,bin); overlap with
    // the wave-level inclusive scan (first 512 lanes = 8 waves own the hist).
    unsigned c = 0u, gb = 0u;
    if (t < NBINS_MAX) {
        c  = s_hist[t];
        gb = c ? (unsigned)atomicAdd(&cnt[t], (int)c) : 0u;
    }
    unsigned v = c;
#pragma unroll
    for (int d = 1; d < 64; d <<= 1) {
        unsigned o = __shfl_up(v, d, 64);
        if ((t & 63) >= d) v += o;
    }
    if (t < NBINS_MAX && (t & 63) == 63) s_wtot[t >> 6] = v;
    __syncthreads();
    if (t < NBINS_MAX) {
        unsigned off = 0;
#pragma unroll
        for (int w = 0; w < 8; ++w)
            if (w < (t >> 6)) off += s_wtot[w];
        const unsigned incl = v + off;
        s_incl[t]  = incl;
        s_gbase[t] = gb - (incl - c);  // pre-biased: drain g = s_gbase[b] + j
    }
    __syncthreads();

    // physical reorder into LDS (sorted position = excl[bin] + rank)
#pragma unroll
    for (int k = 0; k < PPB / K1T; ++k) {
        if (pbin[k] >= 0) {
            int b = pbin[k];
            unsigned sp = s_incl[b] - s_hist[b] + rank[k];
            s_pay[sp] = pay[k];
            s_bin[sp] = (unsigned short)b;
        }
    }
    __syncthreads();

    // linear drain: consecutive sorted particles -> consecutive slot addrs
    for (int j = t; j < np; j += K1T) {
        int b = s_bin[j];
        unsigned g = s_gbase[b] + (unsigned)j;   // gbase + (j - excl), mod 2^32
        if (g < CAP) slots[(size_t)b * CAP + g] = s_pay[j];
    }
}

// ---------------- K2: per-bin u64 tile, two XCD-paired passes -------------

__global__ void __launch_bounds__(512)
accumulate_bins_pass(const float4* __restrict__ slots,
                     const int*    __restrict__ cnt,
                     float*        __restrict__ tiles_w,    // nbins*TILE3
                     float*        __restrict__ tiles_wp) { // nbins*TILE3
    __shared__ unsigned long long t_acc[TILE3];   // 46.7 KB
    // XCD-paired mapping: bin's two passes are 8 blocks apart -> same XCD
    // (round-robin dispatch) -> pass B's slot reads hit that XCD's L2.
    const int x     = blockIdx.x;
    const int which = (x >> 3) & 1;               // 0: w, 1: w*p
    const int bin   = ((x >> 4) << 3) | (x & 7);
    const int tid   = threadIdx.x;

    for (int j = tid; j < TILE3; j += 512) t_acc[j] = 0ull;
    __syncthreads();

    const int n = min(cnt[bin], CAP);
    // bin = ((batch*4 + bbx)*4 + bby)*4 + bbz
    const int bx0 = ((bin >> 4) & 3) * BIN;
    const int by0 = ((bin >> 2) & 3) * BIN;
    const int bz0 = (bin & 3) * BIN;
    const float4* sbase = slots + (size_t)bin * CAP;

    for (int s = tid; s < n; s += 512) {
        float4 r = sbase[s];                         // coalesced 16B load
        float xp = r.x * INV_DX;                     // pos pre-clipped in K1
        float yp = r.y * INV_DX;
        float zp = r.z * INV_DX;
        int bx = (int)xp, by = (int)yp, bz = (int)zp;
        // defensive: an anomalous slot must never index LDS out of bounds
        int l0x = bx - bx0, l0y = by - by0, l0z = bz - bz0;
        if (((l0x | l0y | l0z) & ~15) != 0) continue;
        float wx[3], wy[3], wz[3];
        bspline_w(xp - (float)bx, wx);
        bspline_w(yp - (float)by, wy);
        bspline_w(zp - (float)bz, wz);
        // pre-scale z weights by 2^42 so the tap product is already fixed
        // point (saves a mul per tap vs scaling inside the convert)
        wz[0] *= FXS; wz[1] *= FXS; wz[2] *= FXS;
        float p = which ? r.w : 1.0f;                // unify both passes
#pragma unroll
        for (int a = 0; a < 3; ++a) {
            int ix = (l0x + a) * TILE;
#pragma unroll
            for (int cc = 0; cc < 3; ++cc) {
                int ixy = (ix + l0y + cc) * TILE;
                float wxy = wx[a] * wy[cc] * p;
#pragma unroll
                for (int e = 0; e < 3; ++e) {
                    float v = wxy * wz[e];
                    atomicAdd(&t_acc[ixy + l0z + e],
                              (unsigned long long)v);
                }
            }
        }
    }
    __syncthreads();

    float* gt = (which ? tiles_wp : tiles_w) + (size_t)bin * TILE3;
    for (int j = tid; j < TILE3; j += 512) {
        gt[j] = (float)t_acc[j] * INV_FXS;
    }
}

// ---------------- K3: gather overlapping tiles + divide -------------------

__global__ void finalize_tiles(const float* __restrict__ tiles_w,
                               const float* __restrict__ tiles_wp,
                               float*       __restrict__ out,
                               int total) {
    int c = blockIdx.x * blockDim.x + threadIdx.x;
    if (c >= total) return;
    int cz = c & 63, cy = (c >> 6) & 63, cx = (c >> 12) & 63, b = c >> 18;
    int bx = cx >> 4, mx = cx & 15;
    int by = cy >> 4, my = cy & 15;
    int bz = cz >> 4, mz = cz & 15;

    // per-axis list of (bin coord, tile-local index) covering this cell
    int xb[2], xl[2], nx = 1; xb[0] = bx; xl[0] = mx + 1;
    if (mx == 0 && bx > 0)            { xb[1] = bx - 1; xl[1] = TILE - 1; nx = 2; }
    else if (mx == 15 && bx < NBX - 1){ xb[1] = bx + 1; xl[1] = 0;        nx = 2; }
    int yb[2], yl[2], ny = 1; yb[0] = by; yl[0] = my + 1;
    if (my == 0 && by > 0)            { yb[1] = by - 1; yl[1] = TILE - 1; ny = 2; }
    else if (my == 15 && by < NBX - 1){ yb[1] = by + 1; yl[1] = 0;        ny = 2; }
    int zb[2], zl[2], nz = 1; zb[0] = bz; zl[0] = mz + 1;
    if (mz == 0 && bz > 0)            { zb[1] = bz - 1; zl[1] = TILE - 1; nz = 2; }
    else if (mz == 15 && bz < NBX - 1){ zb[1] = bz + 1; zl[1] = 0;        nz = 2; }

    float w = 0.f, wp = 0.f;
    for (int i = 0; i < nx; ++i)
        for (int j = 0; j < ny; ++j)
            for (int k = 0; k < nz; ++k) {
                int bin = ((b * NBX + xb[i]) * NBX + yb[j]) * NBX + zb[k];
                size_t idx = (size_t)bin * TILE3
                             + (xl[i] * TILE + yl[j]) * TILE + zl[k];
                w  += tiles_w[idx];
                wp += tiles_wp[idx];
            }
    out[c] = wp / (w + EPS_DIV);
}

// ---------------- fallback kernels (v1) -----------------------------------

__global__ void scatter_interleaved(const float* __restrict__ pos,
                                    const float* __restrict__ prob,
                                    const int*   __restrict__ bidx,
                                    float2*      __restrict__ grid,
                                    int L) {
    int i = blockIdx.x * blockDim.x + threadIdx.x;
    if (i >= L) return;
    float xp = clip01(pos[3 * i + 0]) * INV_DX;
    float yp = clip01(pos[3 * i + 1]) * INV_DX;
    float zp = clip01(pos[3 * i + 2]) * INV_DX;
    int bx = (int)xp, by = (int)yp, bz = (int)zp;
    float wx[3], wy[3], wz[3];
    bspline_w(xp - (float)bx, wx);
    bspline_w(yp - (float)by, wy);
    bspline_w(zp - (float)bz, wz);
    float p = prob[i];
    float2* gbase = grid + (size_t)bidx[i] * G3;
#pragma unroll
    for (int a = 0; a < 3; ++a) {
        int tx = bx + a - 1;
        if (tx < 0 || tx >= G) continue;
#pragma unroll
        for (int c = 0; c < 3; ++c) {
            int ty = by + c - 1;
            if (ty < 0 || ty >= G) continue;
            float wxy = wx[a] * wy[c];
            int rowoff = (tx * G + ty) * G;
#pragma unroll
            for (int e = 0; e < 3; ++e) {
                int tz = bz + e - 1;
                if (tz < 0 || tz >= G) continue;
                float w = wxy * wz[e];
                float2* cell = gbase + rowoff + tz;
                atomicAdd(&cell->x, w);
                atomicAdd(&cell->y, w * p);
            }
        }
    }
}

__global__ void finalize_interleaved(const float2* __restrict__ grid,
                                     float* __restrict__ out, int n) {
    int i = blockIdx.x * blockDim.x + threadIdx.x;
    if (i >= n) return;
    float2 c = grid[i];
    out[i] = c.y / (c.x + EPS_DIV);
}

} // anonymous namespace

extern "C" void kernel_launch(void* const* d_in, const int* in_sizes, int n_in,
                              void* d_out, int out_size, void* d_ws, size_t ws_size,
                              hipStream_t stream) {
    const float* pos  = (const float*)d_in[0];
    const float* prob = (const float*)d_in[1];
    const int*   bidx = (const int*)d_in[2];
    float* out = (float*)d_out;

    const int L = in_sizes[1];            // prob has L elements
    const int B = out_size / G3;          // out_size == B * G3
    const int nbins = B * BINS_PB;

    const int threads = 256;
    const int k1blocks = (L + PPB - 1) / PPB;
    const int pblocks  = (L + threads - 1) / threads;
    const int fblocks  = (out_size + threads - 1) / threads;

    // ws: [tiles_w: nbins*TILE3*4B][tiles_wp: same][slots: nbins*CAP*16B][cnt]
    const size_t tilesw_bytes = (size_t)nbins * TILE3 * sizeof(float);
    const size_t slots_bytes  = (size_t)nbins * CAP * sizeof(float4);
    const size_t cnt_bytes    = (size_t)nbins * sizeof(int);
    const size_t need         = 2 * tilesw_bytes + slots_bytes + cnt_bytes;

    if (ws_size >= need && nbins <= NBINS_MAX && (nbins & 7) == 0) {
        float*  tiles_w  = (float*)d_ws;
        float*  tiles_wp = (float*)((char*)d_ws + tilesw_bytes);
        float4* slots    = (float4*)((char*)d_ws + 2 * tilesw_bytes);
        int*    cnt      = (int*)((char*)d_ws + 2 * tilesw_bytes + slots_bytes);

        hipMemsetAsync(cnt, 0, cnt_bytes, stream);
        bin_sort_mat<<<k1blocks, K1T, 0, stream>>>(pos, prob, bidx,
                                                   cnt, slots, L);
        accumulate_bins_pass<<<nbins * 2, 512, 0, stream>>>(slots, cnt,
                                                            tiles_w, tiles_wp);
        finalize_tiles<<<fblocks, threads, 0, stream>>>(tiles_w, tiles_wp,
                                                        out, out_size);
    } else if (ws_size >= (size_t)out_size * 2 * sizeof(float)) {
        // v1 fallback: interleaved global-atomic scatter
        float2* grid = (float2*)d_ws;
        hipMemsetAsync(d_ws, 0, (size_t)out_size * 2 * sizeof(float), stream);
        scatter_interleaved<<<pblocks, threads, 0, stream>>>(pos, prob, bidx, grid, L);
        finalize_interleaved<<<fblocks, threads, 0, stream>>>(grid, out, out_size);
    }
}